// Round 9
// baseline (1482.388 us; speedup 1.0000x reference)
//
#include <hip/hip_runtime.h>
#include <hip/hip_bf16.h>
#include <math.h>

#define BGR   8192        // graphs
#define NND   9           // nodes per graph
#define BN    73728       // BGR*NND
#define NE    131072      // BGR*16 explicit edges
#define ETOT  204800      // NE + BN (self loops)
#define H     128
#define MH    256
#define FIN   15

typedef __bf16 bf16_t;
typedef bf16_t bf16x8 __attribute__((ext_vector_type(8)));
typedef float  f32x4  __attribute__((ext_vector_type(4)));
typedef float  f32x16 __attribute__((ext_vector_type(16)));

__device__ __forceinline__ unsigned short f2bf(float f) {
    unsigned int u = __float_as_uint(f);
    u += 0x7fff + ((u >> 16) & 1);           // RNE (inputs are finite)
    return (unsigned short)(u >> 16);
}
__device__ __forceinline__ unsigned int pkbf(float a, float b) {
    union { __hip_bfloat162 h; unsigned int u; } un;
    un.h = __float22bfloat162_rn(make_float2(a, b));
    return un.u;
}
__device__ __forceinline__ bf16x8 as_frag(int4 v) {
    union { int4 i; bf16x8 f; } u; u.i = v; return u.f;
}
__device__ __forceinline__ float fast_tanh(float v) {
    float e = __expf(2.0f * v);
    return 1.0f - __fdividef(2.0f, e + 1.0f);
}
// 16-deep XOR swizzle for 32-row MFMA fragments (2 lanes/bank = free)
__device__ __forceinline__ int sw16(int m, int k) {
    return m * 256 + ((((k >> 3) ^ (m & 15)) << 3) | (k & 7));
}
// legacy 8-deep swizzle (16x16 kernels: gru, dec)
__device__ __forceinline__ int sw_off(int m, int k) {
    return m * 256 + ((((k >> 3) ^ (m & 7)) << 3) | (k & 7));
}

// ---------------------------------------------------------------- deg kernel
__global__ void deg_kernel(const int* __restrict__ edges, float* __restrict__ inv_deg) {
    int g = blockIdx.x * 256 + threadIdx.x;
    if (g >= BGR) return;
    int cnt[NND];
#pragma unroll
    for (int n = 0; n < NND; ++n) cnt[n] = 1;   // self loop
    for (int j = 0; j < 16; ++j) {
        int d = edges[g * 32 + 16 + j];
#pragma unroll
        for (int n = 0; n < NND; ++n) cnt[n] += (d == n) ? 1 : 0;
    }
#pragma unroll
    for (int n = 0; n < NND; ++n) inv_deg[g * NND + n] = 1.0f / (float)cnt[n];
}

// ---------------------------------------------------------------- encoder
__global__ void enc_kernel(const float* __restrict__ obs, const float* __restrict__ W,
                           const float* __restrict__ b, float* __restrict__ x) {
    int tid = blockIdx.x * 256 + threadIdx.x;     // BN*128 threads
    int i = tid >> 7, h = tid & 127;
    float acc = b[h];
#pragma unroll
    for (int k = 0; k < FIN; ++k) acc += obs[i * FIN + k] * W[k * H + h];
    x[i * H + h] = tanhf(acc);
}

// ---------------------------------------------------------------- weight transpose+bf16
// out: [W1T 4x256x256][W2T 4x256x256][W3T 4x128x256][WG 4x512x256][dW1T 256x128][dW2T 256x256]
// WG packed col p = w*64 + gate*16 + c  ->  (gate, h = w*16 + c), w=0..7
__global__ void wt_kernel(const float* __restrict__ W1, const float* __restrict__ W2,
                          const float* __restrict__ W3, const float* __restrict__ Wi,
                          const float* __restrict__ Wh, const float* __restrict__ dW1,
                          const float* __restrict__ dW2, unsigned short* __restrict__ out) {
    int idx = blockIdx.x * 256 + threadIdx.x;     // 1277952 total
    float v;
    if (idx < 262144) {
        int s = idx >> 16, r = idx & 65535, n = r >> 8, k = r & 255;
        v = W1[(s << 16) + (k << 8) + n];
    } else if (idx < 524288) {
        int i2 = idx - 262144;
        int s = i2 >> 16, r = i2 & 65535, n = r >> 8, k = r & 255;
        v = W2[(s << 16) + (k << 8) + n];
    } else if (idx < 655360) {
        int i3 = idx - 524288;
        int s = i3 >> 15, r = i3 & 32767, n = r >> 8, k = r & 255;
        v = W3[(s << 15) + (k << 7) + n];
    } else if (idx < 1179648) {
        int i4 = idx - 655360;                    // 0..524287
        int s = i4 >> 17, rr = i4 & 131071;
        int p = rr >> 8, k = rr & 255;
        int w = p >> 6, rem = p & 63;
        int gate = rem >> 4, c = rem & 15;
        int h = w * 16 + c;
        const int sb = s * 49152;                 // 128*384
        if (gate == 0)      v = (k < 128) ? Wi[sb + k * 384 + h]       : Wh[sb + (k - 128) * 384 + h];
        else if (gate == 1) v = (k < 128) ? Wi[sb + k * 384 + 128 + h] : Wh[sb + (k - 128) * 384 + 128 + h];
        else if (gate == 2) v = (k < 128) ? Wi[sb + k * 384 + 256 + h] : 0.f;
        else                v = (k < 128) ? 0.f                        : Wh[sb + (k - 128) * 384 + 256 + h];
    } else if (idx < 1212416) {
        int i5 = idx - 1179648;                   // dW1T [256][128]
        int n = i5 >> 7, k = i5 & 127;
        v = dW1[k * 256 + n];
    } else {
        int i6 = idx - 1212416;                   // dW2T [256][256]
        int n = i6 >> 8, k = i6 & 255;
        v = dW2[k * 256 + n];
    }
    out[idx] = f2bf(v);
}

// ---------------------------------------------------------------- fused msg MLP, 32x32x16 MFMA bf16
// 64 edges / block, 512 threads (8 waves). Layers 1-2: wave w owns n-tile w*32,
// both 32-row m-tiles. Layer 3: wave = (m-tile wv&1, n-tile wv>>1).
// SINGLE 32 KB LDS buffer (read phase | barrier | write phase) -> 33 KB total
// -> 3 blocks/CU at __launch_bounds__(512,6); reg cap 85 >= measured 56 (no spill).
__global__ __launch_bounds__(512, 6) void msg_mfma(
        const float* __restrict__ x, const int* __restrict__ edges,
        const unsigned short* __restrict__ W1T, const float* __restrict__ b1,
        const unsigned short* __restrict__ W2T, const float* __restrict__ b2,
        const unsigned short* __restrict__ W3T,
        float* __restrict__ aggr) {
    __shared__ unsigned short buf[64 * 256];   // 32 KB, swizzled [m][k]
    __shared__ int sdst[64];
    const int t  = threadIdx.x;
    const int e0 = blockIdx.x * 64;
    const int wv = t >> 6;        // 0..7
    const int ln = t & 63;
    const int l31 = ln & 31;
    const int lh  = ln >> 5;      // k-half selector

    // ---- stage A0 = bf16(concat(x[dst], x[src])); also dst indices
    if (t < 64) {
        const int eg = e0 + t;
        sdst[t] = (eg < NE) ? ((eg >> 4) * NND + edges[(eg >> 4) * 32 + 16 + (eg & 15)])
                            : (eg - NE);
    }
    {
        const int row  = t >> 2;          // 0..127
        const int q    = t & 3;
        const int e    = row & 63;
        const int side = row >> 6;        // 0 -> dst cols 0..127, 1 -> src cols 128..255
        const int eg   = e0 + e;
        int node;
        if (eg < NE) {
            int g = eg >> 4, j = eg & 15;
            node = g * NND + (side ? edges[g * 32 + j] : edges[g * 32 + 16 + j]);
        } else {
            node = eg - NE;
        }
        const float* xs = x + (size_t)node * H + q * 32;
        const int kbase = side * 128 + q * 32;
#pragma unroll
        for (int i = 0; i < 8; ++i) {
            float4 v = *(const float4*)(xs + i * 4);
            uint2 o;
            o.x = pkbf(v.x, v.y); o.y = pkbf(v.z, v.w);
            *(uint2*)(buf + sw16(e, kbase + i * 4)) = o;
        }
    }
    __syncthreads();   // barrier 1: staging visible

    // ---- layer 1: read buf (acc in regs), then overwrite buf with act1
    {
        f32x16 acc0, acc1;
#pragma unroll
        for (int i = 0; i < 16; ++i) { acc0[i] = 0.f; acc1[i] = 0.f; }
        const unsigned short* wp = W1T + (size_t)(wv * 32 + l31) * 256 + lh * 8;
#pragma unroll
        for (int ks = 0; ks < 16; ++ks) {
            const int kk = ks * 16 + lh * 8;
            bf16x8 a0 = as_frag(*(const int4*)(buf + sw16(l31, kk)));
            bf16x8 a1 = as_frag(*(const int4*)(buf + sw16(32 + l31, kk)));
            bf16x8 bw = as_frag(*(const int4*)(wp + ks * 16));
            acc0 = __builtin_amdgcn_mfma_f32_32x32x16_bf16(a0, bw, acc0, 0, 0, 0);
            acc1 = __builtin_amdgcn_mfma_f32_32x32x16_bf16(a1, bw, acc1, 0, 0, 0);
        }
        __syncthreads();   // barrier 2: all reads done
        const int n = wv * 32 + l31;
        const float bias = b1[n];
#pragma unroll
        for (int reg = 0; reg < 16; ++reg) {
            const int mrow = (reg & 3) + ((reg >> 2) << 3) + (lh << 2);
            buf[sw16(mrow, n)]      = f2bf(fast_tanh(acc0[reg] + bias));
            buf[sw16(32 + mrow, n)] = f2bf(fast_tanh(acc1[reg] + bias));
        }
    }
    __syncthreads();   // barrier 3: act1 visible

    // ---- layer 2: read buf, overwrite with act2
    {
        f32x16 acc0, acc1;
#pragma unroll
        for (int i = 0; i < 16; ++i) { acc0[i] = 0.f; acc1[i] = 0.f; }
        const unsigned short* wp = W2T + (size_t)(wv * 32 + l31) * 256 + lh * 8;
#pragma unroll
        for (int ks = 0; ks < 16; ++ks) {
            const int kk = ks * 16 + lh * 8;
            bf16x8 a0 = as_frag(*(const int4*)(buf + sw16(l31, kk)));
            bf16x8 a1 = as_frag(*(const int4*)(buf + sw16(32 + l31, kk)));
            bf16x8 bw = as_frag(*(const int4*)(wp + ks * 16));
            acc0 = __builtin_amdgcn_mfma_f32_32x32x16_bf16(a0, bw, acc0, 0, 0, 0);
            acc1 = __builtin_amdgcn_mfma_f32_32x32x16_bf16(a1, bw, acc1, 0, 0, 0);
        }
        __syncthreads();   // barrier 4: all reads done
        const int n = wv * 32 + l31;
        const float bias = b2[n];
#pragma unroll
        for (int reg = 0; reg < 16; ++reg) {
            const int mrow = (reg & 3) + ((reg >> 2) << 3) + (lh << 2);
            buf[sw16(mrow, n)]      = f2bf(fast_tanh(acc0[reg] + bias));
            buf[sw16(32 + mrow, n)] = f2bf(fast_tanh(acc1[reg] + bias));
        }
    }
    __syncthreads();   // barrier 5: act2 visible

    // ---- layer 3: read buf; N=128; wave (mt = wv&1, nq = wv>>1); atomic scatter
    {
        const int mt = wv & 1, nq = wv >> 1;
        const int n = nq * 32 + l31;
        f32x16 acc;
#pragma unroll
        for (int i = 0; i < 16; ++i) acc[i] = 0.f;
        const unsigned short* wp = W3T + (size_t)n * 256 + lh * 8;
#pragma unroll
        for (int ks = 0; ks < 16; ++ks) {
            const int kk = ks * 16 + lh * 8;
            bf16x8 a = as_frag(*(const int4*)(buf + sw16(mt * 32 + l31, kk)));
            bf16x8 bw = as_frag(*(const int4*)(wp + ks * 16));
            acc = __builtin_amdgcn_mfma_f32_32x32x16_bf16(a, bw, acc, 0, 0, 0);
        }
#pragma unroll
        for (int reg = 0; reg < 16; ++reg) {
            const int m = mt * 32 + (reg & 3) + ((reg >> 2) << 3) + (lh << 2);
            atomicAdd(aggr + (size_t)sdst[m] * H + n, acc[reg]);
        }
    }
}

// ---------------------------------------------------------------- GRU via MFMA (64 nodes / block, 512 thr)
// Wave w owns packed cols w*64..w*64+63 = all 4 gates of h-slice w*16..w*16+15.
__global__ __launch_bounds__(512, 4) void gru_mfma(
        float* __restrict__ x, float* __restrict__ aggr, const float* __restrict__ inv_deg,
        const unsigned short* __restrict__ WG, const float* __restrict__ b3m,
        const float* __restrict__ bi, const float* __restrict__ bh) {
    __shared__ unsigned short bufA[64 * 256];   // 32 KB
    const int t = threadIdx.x;
    const int n0 = blockIdx.x * 64;
    const int wv = t >> 6, ln = t & 63, lrow = ln & 15, lq = ln >> 4;

    // stage A = bf16([aggr*inv_deg + b3 | x]): m = t>>3, k-slice q*32
    {
        const int m = t >> 3;
        const int q = t & 7;
        const int k0 = q * 32;
        const int node = n0 + m;
        if (q < 4) {
            const float scale = inv_deg[node];
            const float* src = aggr + (size_t)node * H + k0;
#pragma unroll
            for (int i = 0; i < 8; ++i) {
                float4 v = *(const float4*)(src + i * 4);
                const float4 bb = *(const float4*)(b3m + k0 + i * 4);
                v.x = v.x * scale + bb.x; v.y = v.y * scale + bb.y;
                v.z = v.z * scale + bb.z; v.w = v.w * scale + bb.w;
                uint2 o; o.x = pkbf(v.x, v.y); o.y = pkbf(v.z, v.w);
                *(uint2*)(bufA + sw_off(m, k0 + i * 4)) = o;
            }
        } else {
            const float* src = x + (size_t)node * H + (k0 - 128);
#pragma unroll
            for (int i = 0; i < 8; ++i) {
                float4 v = *(const float4*)(src + i * 4);
                uint2 o; o.x = pkbf(v.x, v.y); o.y = pkbf(v.z, v.w);
                *(uint2*)(bufA + sw_off(m, k0 + i * 4)) = o;
            }
        }
    }
    __syncthreads();

    const f32x4 zero = {0.f, 0.f, 0.f, 0.f};
    f32x4 acc[4][4];    // [m-tile][gate]
#pragma unroll
    for (int i = 0; i < 4; ++i)
#pragma unroll
        for (int j = 0; j < 4; ++j) acc[i][j] = zero;

    const unsigned short* wgp = WG + (size_t)(wv * 64 + lrow) * 256;
#pragma unroll
    for (int kq = 0; kq < 8; ++kq) {
        const int ko = kq * 32 + lq * 8;
        bf16x8 af[4], bfr[4];
#pragma unroll
        for (int tm = 0; tm < 4; ++tm)
            af[tm] = as_frag(*(const int4*)(bufA + sw_off(tm * 16 + lrow, ko)));
#pragma unroll
        for (int g = 0; g < 4; ++g)
            bfr[g] = as_frag(*(const int4*)(wgp + (size_t)g * 16 * 256 + ko));
#pragma unroll
        for (int tm = 0; tm < 4; ++tm)
#pragma unroll
            for (int g = 0; g < 4; ++g)
                acc[tm][g] = __builtin_amdgcn_mfma_f32_16x16x32_bf16(af[tm], bfr[g], acc[tm][g], 0, 0, 0);
    }

    // epilogue: thread-local gate mixing for h = wv*16 + lrow
    {
        const int h = wv * 16 + lrow;
        const float b_r = bi[h] + bh[h];
        const float b_z = bi[128 + h] + bh[128 + h];
        const float b_n = bi[256 + h];
        const float b_h = bh[256 + h];
#pragma unroll
        for (int tm = 0; tm < 4; ++tm) {
#pragma unroll
            for (int r = 0; r < 4; ++r) {
                const int node = n0 + tm * 16 + lq * 4 + r;
                const float irhr = acc[tm][0][r] + b_r;
                const float izhz = acc[tm][1][r] + b_z;
                const float inn  = acc[tm][2][r] + b_n;
                const float hn   = acc[tm][3][r] + b_h;
                const float rg = 1.f / (1.f + expf(-irhr));
                const float zg = 1.f / (1.f + expf(-izhz));
                const float ng = tanhf(inn + rg * hn);
                const float xo = x[(size_t)node * H + h];
                x[(size_t)node * H + h] = (1.f - zg) * ng + zg * xo;
                aggr[(size_t)node * H + h] = 0.f;   // re-zero for next step
            }
        }
    }
}

// ---------------------------------------------------------------- decoder via MFMA (64 masked ids / block)
__global__ __launch_bounds__(256, 4) void dec_mfma(
        const float* __restrict__ x,
        const unsigned short* __restrict__ W1T, const float* __restrict__ b1,
        const unsigned short* __restrict__ W2T, const float* __restrict__ b2,
        const float* __restrict__ W3, const float* __restrict__ b3,
        float* __restrict__ out) {
    __shared__ unsigned short buf[64 * 256];   // 32 KB
    const int t = threadIdx.x;
    const int id0 = blockIdx.x * 64;
    const int wv = t >> 6, ln = t & 63, lrow = ln & 15, lq = ln >> 4;
    const int nbase = wv * 64;

    // stage bf16(x) for 64 masked ids into buf[:, 0:128]
    {
        const int m = t >> 2, q = t & 3;
        const int id = id0 + m;
        const int node = (id >> 3) * NND + (id & 7);
        const float* src = x + (size_t)node * H + q * 32;
#pragma unroll
        for (int i = 0; i < 8; ++i) {
            float4 v = *(const float4*)(src + i * 4);
            uint2 o; o.x = pkbf(v.x, v.y); o.y = pkbf(v.z, v.w);
            *(uint2*)(buf + sw_off(m, q * 32 + i * 4)) = o;
        }
    }
    __syncthreads();

    const f32x4 zero = {0.f, 0.f, 0.f, 0.f};

    // ---- layer 1: K=128 -> 256 cols
    {
        f32x4 acc[4][4];
#pragma unroll
        for (int i = 0; i < 4; ++i)
#pragma unroll
            for (int j = 0; j < 4; ++j) acc[i][j] = zero;
#pragma unroll
        for (int kq = 0; kq < 4; ++kq) {
            const int ko = kq * 32 + lq * 8;
            bf16x8 af[4], bfr[4];
#pragma unroll
            for (int tm = 0; tm < 4; ++tm)
                af[tm] = as_frag(*(const int4*)(buf + sw_off(tm * 16 + lrow, ko)));
#pragma unroll
            for (int tn = 0; tn < 4; ++tn)
                bfr[tn] = as_frag(*(const int4*)(W1T + (size_t)(nbase + tn * 16 + lrow) * 128 + ko));
#pragma unroll
            for (int tm = 0; tm < 4; ++tm)
#pragma unroll
                for (int tn = 0; tn < 4; ++tn)
                    acc[tm][tn] = __builtin_amdgcn_mfma_f32_16x16x32_bf16(af[tm], bfr[tn], acc[tm][tn], 0, 0, 0);
        }
        __syncthreads();
#pragma unroll
        for (int tn = 0; tn < 4; ++tn) {
            const int n = nbase + tn * 16 + lrow;
            const float bias = b1[n];
#pragma unroll
            for (int tm = 0; tm < 4; ++tm)
#pragma unroll
                for (int r = 0; r < 4; ++r) {
                    const int m = tm * 16 + lq * 4 + r;
                    buf[sw_off(m, n)] = f2bf(fast_tanh(acc[tm][tn][r] + bias));
                }
        }
    }
    __syncthreads();

    // ---- layer 2: K=256 -> 256 cols
    {
        f32x4 acc[4][4];
#pragma unroll
        for (int i = 0; i < 4; ++i)
#pragma unroll
            for (int j = 0; j < 4; ++j) acc[i][j] = zero;
#pragma unroll
        for (int kq = 0; kq < 8; ++kq) {
            const int ko = kq * 32 + lq * 8;
            bf16x8 af[4], bfr[4];
#pragma unroll
            for (int tm = 0; tm < 4; ++tm)
                af[tm] = as_frag(*(const int4*)(buf + sw_off(tm * 16 + lrow, ko)));
#pragma unroll
            for (int tn = 0; tn < 4; ++tn)
                bfr[tn] = as_frag(*(const int4*)(W2T + (size_t)(nbase + tn * 16 + lrow) * 256 + ko));
#pragma unroll
            for (int tm = 0; tm < 4; ++tm)
#pragma unroll
                for (int tn = 0; tn < 4; ++tn)
                    acc[tm][tn] = __builtin_amdgcn_mfma_f32_16x16x32_bf16(af[tm], bfr[tn], acc[tm][tn], 0, 0, 0);
        }
        __syncthreads();
#pragma unroll
        for (int tn = 0; tn < 4; ++tn) {
            const int n = nbase + tn * 16 + lrow;
            const float bias = b2[n];
#pragma unroll
            for (int tm = 0; tm < 4; ++tm)
#pragma unroll
                for (int r = 0; r < 4; ++r) {
                    const int m = tm * 16 + lq * 4 + r;
                    buf[sw_off(m, n)] = f2bf(fast_tanh(acc[tm][tn][r] + bias));
                }
        }
    }
    __syncthreads();

    // ---- layer 3: 256 -> 1, 4 threads per id, shuffle reduce
    {
        const int m = t >> 2, p = t & 3;
        float s = 0.f;
#pragma unroll
        for (int i = 0; i < 64; ++i) {
            const int k = p * 64 + i;
            const float a = __uint_as_float((unsigned int)buf[sw_off(m, k)] << 16);
            s += a * W3[k];
        }
        s += __shfl_xor(s, 1);
        s += __shfl_xor(s, 2);
        if (p == 0) out[id0 + m] = s + b3[0];
    }
}

// ---------------------------------------------------------------- launch
extern "C" void kernel_launch(void* const* d_in, const int* in_sizes, int n_in,
                              void* d_out, int out_size, void* d_ws, size_t ws_size,
                              hipStream_t stream) {
    const float* obs    = (const float*)d_in[0];
    const int*   edges  = (const int*)  d_in[1];
    const float* enc_W  = (const float*)d_in[2];
    const float* enc_b  = (const float*)d_in[3];
    const float* msg_W1 = (const float*)d_in[4];
    const float* msg_b1 = (const float*)d_in[5];
    const float* msg_W2 = (const float*)d_in[6];
    const float* msg_b2 = (const float*)d_in[7];
    const float* msg_W3 = (const float*)d_in[8];
    const float* msg_b3 = (const float*)d_in[9];
    const float* gru_Wi = (const float*)d_in[10];
    const float* gru_Wh = (const float*)d_in[11];
    const float* gru_bi = (const float*)d_in[12];
    const float* gru_bh = (const float*)d_in[13];
    const float* dec_W1 = (const float*)d_in[14];
    const float* dec_b1 = (const float*)d_in[15];
    const float* dec_W2 = (const float*)d_in[16];
    const float* dec_b2 = (const float*)d_in[17];
    const float* dec_W3 = (const float*)d_in[18];
    const float* dec_b3 = (const float*)d_in[19];

    float* x       = (float*)d_ws;                 // BN*128
    float* aggr    = x + (size_t)BN * H;           // BN*128
    float* inv_deg = aggr + (size_t)BN * H;        // BN
    unsigned short* wbf = (unsigned short*)(inv_deg + BN);   // 1277952 bf16

    hipMemsetAsync(aggr, 0, (size_t)BN * H * sizeof(float), stream);
    deg_kernel<<<(BGR + 255) / 256, 256, 0, stream>>>(edges, inv_deg);
    wt_kernel<<<1277952 / 256, 256, 0, stream>>>(msg_W1, msg_W2, msg_W3, gru_Wi, gru_Wh,
                                                 dec_W1, dec_W2, wbf);
    enc_kernel<<<BN * H / 256, 256, 0, stream>>>(obs, enc_W, enc_b, x);

    for (int s = 0; s < 4; ++s) {
        const unsigned short* W1T = wbf + (size_t)s * 65536;
        const unsigned short* W2T = wbf + 262144 + (size_t)s * 65536;
        const unsigned short* W3T = wbf + 524288 + (size_t)s * 32768;
        const unsigned short* WGs = wbf + 655360 + (size_t)s * 131072;
        msg_mfma<<<ETOT / 64, 512, 0, stream>>>(
            x, edges,
            W1T, msg_b1 + (size_t)s * 256,
            W2T, msg_b2 + (size_t)s * 256,
            W3T,
            aggr);
        gru_mfma<<<BN / 64, 512, 0, stream>>>(
            x, aggr, inv_deg, WGs, msg_b3 + (size_t)s * 128,
            gru_bi + (size_t)s * 384, gru_bh + (size_t)s * 384);
    }

    dec_mfma<<<BGR * 8 / 64, 256, 0, stream>>>(
        x, wbf + 1179648, dec_b1, wbf + 1212416, dec_b2, dec_W3, dec_b3, (float*)d_out);
}

// Round 10
// 1350.772 us; speedup vs baseline: 1.0974x; 1.0974x over previous
//
#include <hip/hip_runtime.h>
#include <hip/hip_bf16.h>
#include <math.h>

#define BGR   8192        // graphs
#define NND   9           // nodes per graph
#define BN    73728       // BGR*NND
#define NE    131072      // BGR*16 explicit edges
#define ETOT  204800      // NE + BN (self loops)
#define H     128
#define MH    256
#define FIN   15

typedef __bf16 bf16_t;
typedef bf16_t bf16x8 __attribute__((ext_vector_type(8)));
typedef float  f32x4  __attribute__((ext_vector_type(4)));
typedef float  f32x16 __attribute__((ext_vector_type(16)));

__device__ __forceinline__ unsigned short f2bf(float f) {
    unsigned int u = __float_as_uint(f);
    u += 0x7fff + ((u >> 16) & 1);           // RNE (inputs are finite)
    return (unsigned short)(u >> 16);
}
__device__ __forceinline__ unsigned int pkbf(float a, float b) {
    union { __hip_bfloat162 h; unsigned int u; } un;
    un.h = __float22bfloat162_rn(make_float2(a, b));
    return un.u;
}
__device__ __forceinline__ bf16x8 as_frag(int4 v) {
    union { int4 i; bf16x8 f; } u; u.i = v; return u.f;
}
__device__ __forceinline__ float fast_tanh(float v) {
    float e = __expf(2.0f * v);
    return 1.0f - __fdividef(2.0f, e + 1.0f);
}
// 16-deep XOR swizzle, K=256 row (32x32 fragments, 2 lanes/bank = free)
__device__ __forceinline__ int sw16(int m, int k) {
    return m * 256 + ((((k >> 3) ^ (m & 15)) << 3) | (k & 7));
}
// 16-deep XOR swizzle, K=128 row (proj staging)
__device__ __forceinline__ int swp(int m, int k) {
    return m * 128 + ((((k >> 3) ^ (m & 15)) << 3) | (k & 7));
}
// legacy 8-deep swizzle (16x16 kernels: gru, dec)
__device__ __forceinline__ int sw_off(int m, int k) {
    return m * 256 + ((((k >> 3) ^ (m & 7)) << 3) | (k & 7));
}

// ---------------------------------------------------------------- deg kernel
__global__ void deg_kernel(const int* __restrict__ edges, float* __restrict__ inv_deg) {
    int g = blockIdx.x * 256 + threadIdx.x;
    if (g >= BGR) return;
    int cnt[NND];
#pragma unroll
    for (int n = 0; n < NND; ++n) cnt[n] = 1;   // self loop
    for (int j = 0; j < 16; ++j) {
        int d = edges[g * 32 + 16 + j];
#pragma unroll
        for (int n = 0; n < NND; ++n) cnt[n] += (d == n) ? 1 : 0;
    }
#pragma unroll
    for (int n = 0; n < NND; ++n) inv_deg[g * NND + n] = 1.0f / (float)cnt[n];
}

// ---------------------------------------------------------------- encoder
__global__ void enc_kernel(const float* __restrict__ obs, const float* __restrict__ W,
                           const float* __restrict__ b, float* __restrict__ x) {
    int tid = blockIdx.x * 256 + threadIdx.x;     // BN*128 threads
    int i = tid >> 7, h = tid & 127;
    float acc = b[h];
#pragma unroll
    for (int k = 0; k < FIN; ++k) acc += obs[i * FIN + k] * W[k * H + h];
    x[i * H + h] = tanhf(acc);
}

// ---------------------------------------------------------------- weight transpose+bf16
// out: [W1T 4x256x256(unused)][W2T 4x256x256][W3T 4x128x256][WG 4x512x256]
//      [dW1T 256x128][dW2T 256x256][W1P 4x512x128]
// W1P col n<256: u-side (W1 rows 0..127); n>=256: v-side (W1 rows 128..255).
__global__ void wt_kernel(const float* __restrict__ W1, const float* __restrict__ W2,
                          const float* __restrict__ W3, const float* __restrict__ Wi,
                          const float* __restrict__ Wh, const float* __restrict__ dW1,
                          const float* __restrict__ dW2, unsigned short* __restrict__ out) {
    int idx = blockIdx.x * 256 + threadIdx.x;     // 1540096 total
    float v;
    if (idx < 262144) {
        int s = idx >> 16, r = idx & 65535, n = r >> 8, k = r & 255;
        v = W1[(s << 16) + (k << 8) + n];
    } else if (idx < 524288) {
        int i2 = idx - 262144;
        int s = i2 >> 16, r = i2 & 65535, n = r >> 8, k = r & 255;
        v = W2[(s << 16) + (k << 8) + n];
    } else if (idx < 655360) {
        int i3 = idx - 524288;
        int s = i3 >> 15, r = i3 & 32767, n = r >> 8, k = r & 255;
        v = W3[(s << 15) + (k << 7) + n];
    } else if (idx < 1179648) {
        int i4 = idx - 655360;                    // 0..524287
        int s = i4 >> 17, rr = i4 & 131071;
        int p = rr >> 8, k = rr & 255;
        int w = p >> 6, rem = p & 63;
        int gate = rem >> 4, c = rem & 15;
        int h = w * 16 + c;
        const int sb = s * 49152;                 // 128*384
        if (gate == 0)      v = (k < 128) ? Wi[sb + k * 384 + h]       : Wh[sb + (k - 128) * 384 + h];
        else if (gate == 1) v = (k < 128) ? Wi[sb + k * 384 + 128 + h] : Wh[sb + (k - 128) * 384 + 128 + h];
        else if (gate == 2) v = (k < 128) ? Wi[sb + k * 384 + 256 + h] : 0.f;
        else                v = (k < 128) ? 0.f                        : Wh[sb + (k - 128) * 384 + 256 + h];
    } else if (idx < 1212416) {
        int i5 = idx - 1179648;                   // dW1T [256][128]
        int n = i5 >> 7, k = i5 & 127;
        v = dW1[k * 256 + n];
    } else if (idx < 1277952) {
        int i6 = idx - 1212416;                   // dW2T [256][256]
        int n = i6 >> 8, k = i6 & 255;
        v = dW2[k * 256 + n];
    } else {
        int i7 = idx - 1277952;                   // W1P [s][n:512][k:128]
        int s = i7 >> 16, rr = i7 & 65535;
        int n = rr >> 7, k = rr & 127;
        v = (n < 256) ? W1[(s << 16) + (k << 8) + n]
                      : W1[(s << 16) + ((k + 128) << 8) + (n - 256)];
    }
    out[idx] = f2bf(v);
}

// ---------------------------------------------------------------- per-node projection P = x @ [U|V]
// 64 nodes/block, 512 thr (8 waves). Wave w: cols [w*64, w*64+64), 2x2 32-tiles.
__global__ __launch_bounds__(512, 4) void proj_mfma(
        const float* __restrict__ x, const unsigned short* __restrict__ W1P,
        unsigned short* __restrict__ P) {
    __shared__ unsigned short lbuf[64 * 128];   // 16 KB
    const int t = threadIdx.x;
    const int n0 = blockIdx.x * 64;             // node base
    const int wv = t >> 6, ln = t & 63, l31 = ln & 31, lh = ln >> 5;

    // stage bf16(x) rows: 8 thr/row, 16 cols each
    {
        const int m = t >> 3, q = t & 7;
        const float* xs = x + (size_t)(n0 + m) * H + q * 16;
#pragma unroll
        for (int i = 0; i < 4; ++i) {
            float4 v = *(const float4*)(xs + i * 4);
            uint2 o; o.x = pkbf(v.x, v.y); o.y = pkbf(v.z, v.w);
            *(uint2*)(lbuf + swp(m, q * 16 + i * 4)) = o;
        }
    }
    __syncthreads();

    f32x16 acc[2][2];
#pragma unroll
    for (int a = 0; a < 2; ++a)
#pragma unroll
        for (int b = 0; b < 2; ++b)
#pragma unroll
            for (int i = 0; i < 16; ++i) acc[a][b][i] = 0.f;

    const int nb = wv * 64;
    const unsigned short* wp0 = W1P + (size_t)(nb + l31) * 128 + lh * 8;
    const unsigned short* wp1 = W1P + (size_t)(nb + 32 + l31) * 128 + lh * 8;
#pragma unroll
    for (int ks = 0; ks < 8; ++ks) {
        const int kk = ks * 16 + lh * 8;
        bf16x8 a0 = as_frag(*(const int4*)(lbuf + swp(l31, kk)));
        bf16x8 a1 = as_frag(*(const int4*)(lbuf + swp(32 + l31, kk)));
        bf16x8 w0 = as_frag(*(const int4*)(wp0 + ks * 16));
        bf16x8 w1 = as_frag(*(const int4*)(wp1 + ks * 16));
        acc[0][0] = __builtin_amdgcn_mfma_f32_32x32x16_bf16(a0, w0, acc[0][0], 0, 0, 0);
        acc[0][1] = __builtin_amdgcn_mfma_f32_32x32x16_bf16(a0, w1, acc[0][1], 0, 0, 0);
        acc[1][0] = __builtin_amdgcn_mfma_f32_32x32x16_bf16(a1, w0, acc[1][0], 0, 0, 0);
        acc[1][1] = __builtin_amdgcn_mfma_f32_32x32x16_bf16(a1, w1, acc[1][1], 0, 0, 0);
    }

    // epilogue: P[node][col] bf16 (stores coalesce: lanes 0..31 = consecutive cols)
#pragma unroll
    for (int mt = 0; mt < 2; ++mt)
#pragma unroll
        for (int nt = 0; nt < 2; ++nt) {
            const int col = nb + nt * 32 + l31;
#pragma unroll
            for (int reg = 0; reg < 16; ++reg) {
                const int mrow = mt * 32 + (reg & 3) + ((reg >> 2) << 3) + (lh << 2);
                P[(size_t)(n0 + mrow) * 512 + col] = f2bf(acc[mt][nt][reg]);
            }
        }
}

// ---------------------------------------------------------------- fused msg MLP (layers 2-3), 32x32x16
// 64 edges/block, 512 thr. Stage act1 = tanh(u_dst + v_src + b1) directly (layer 1
// pre-computed per-node by proj_mfma). Dual LDS buffers -> ONLY 2 barriers.
__global__ __launch_bounds__(512, 4) void msg_mfma(
        const unsigned short* __restrict__ P, const int* __restrict__ edges,
        const float* __restrict__ b1,
        const unsigned short* __restrict__ W2T, const float* __restrict__ b2,
        const unsigned short* __restrict__ W3T,
        float* __restrict__ aggr) {
    __shared__ unsigned short bufA[64 * 256];   // 32 KB: act1
    __shared__ unsigned short bufB[64 * 256];   // 32 KB: act2
    __shared__ int sdst[64];
    const int t  = threadIdx.x;
    const int e0 = blockIdx.x * 64;
    const int wv = t >> 6;        // 0..7
    const int ln = t & 63;
    const int l31 = ln & 31;
    const int lh  = ln >> 5;

    // ---- stage act1: 8 thr/edge, 32 cols each; also dst indices
    if (t < 64) {
        const int eg = e0 + t;
        sdst[t] = (eg < NE) ? ((eg >> 4) * NND + edges[(eg >> 4) * 32 + 16 + (eg & 15)])
                            : (eg - NE);
    }
    {
        const int row = t >> 3;          // edge slot 0..63
        const int c0  = (t & 7) * 32;
        const int eg  = e0 + row;
        int dn, sn;
        if (eg < NE) {
            int g = eg >> 4, j = eg & 15;
            sn = g * NND + edges[g * 32 + j];
            dn = g * NND + edges[g * 32 + 16 + j];
        } else {
            dn = sn = eg - NE;
        }
        const unsigned short* up = P + (size_t)dn * 512 + c0;
        const unsigned short* vp = P + (size_t)sn * 512 + 256 + c0;
#pragma unroll
        for (int i = 0; i < 4; ++i) {
            const uint4 uu = *(const uint4*)(up + i * 8);
            const uint4 vv = *(const uint4*)(vp + i * 8);
            const unsigned int ua[4] = {uu.x, uu.y, uu.z, uu.w};
            const unsigned int va[4] = {vv.x, vv.y, vv.z, vv.w};
            unsigned int op[4];
#pragma unroll
            for (int j = 0; j < 4; ++j) {
                const float2 bb = *(const float2*)(b1 + c0 + i * 8 + j * 2);
                const float s0 = fast_tanh(__uint_as_float(ua[j] << 16) +
                                           __uint_as_float(va[j] << 16) + bb.x);
                const float s1 = fast_tanh(__uint_as_float(ua[j] & 0xffff0000u) +
                                           __uint_as_float(va[j] & 0xffff0000u) + bb.y);
                op[j] = pkbf(s0, s1);
            }
            *(uint4*)(bufA + sw16(row, c0 + i * 8)) = make_uint4(op[0], op[1], op[2], op[3]);
        }
    }
    __syncthreads();   // barrier 1: act1 + sdst visible

    // ---- layer 2: read bufA, write act2 to bufB (no barrier needed between)
    {
        f32x16 acc0, acc1;
#pragma unroll
        for (int i = 0; i < 16; ++i) { acc0[i] = 0.f; acc1[i] = 0.f; }
        const unsigned short* wp = W2T + (size_t)(wv * 32 + l31) * 256 + lh * 8;
#pragma unroll
        for (int ks = 0; ks < 16; ++ks) {
            const int kk = ks * 16 + lh * 8;
            bf16x8 a0 = as_frag(*(const int4*)(bufA + sw16(l31, kk)));
            bf16x8 a1 = as_frag(*(const int4*)(bufA + sw16(32 + l31, kk)));
            bf16x8 bw = as_frag(*(const int4*)(wp + ks * 16));
            acc0 = __builtin_amdgcn_mfma_f32_32x32x16_bf16(a0, bw, acc0, 0, 0, 0);
            acc1 = __builtin_amdgcn_mfma_f32_32x32x16_bf16(a1, bw, acc1, 0, 0, 0);
        }
        const int n = wv * 32 + l31;
        const float bias = b2[n];
#pragma unroll
        for (int reg = 0; reg < 16; ++reg) {
            const int mrow = (reg & 3) + ((reg >> 2) << 3) + (lh << 2);
            bufB[sw16(mrow, n)]      = f2bf(fast_tanh(acc0[reg] + bias));
            bufB[sw16(32 + mrow, n)] = f2bf(fast_tanh(acc1[reg] + bias));
        }
    }
    __syncthreads();   // barrier 2: act2 visible

    // ---- layer 3: read bufB; N=128; wave (mt = wv&1, nq = wv>>1); atomic scatter
    {
        const int mt = wv & 1, nq = wv >> 1;
        const int n = nq * 32 + l31;
        f32x16 acc;
#pragma unroll
        for (int i = 0; i < 16; ++i) acc[i] = 0.f;
        const unsigned short* wp = W3T + (size_t)n * 256 + lh * 8;
#pragma unroll
        for (int ks = 0; ks < 16; ++ks) {
            const int kk = ks * 16 + lh * 8;
            bf16x8 a = as_frag(*(const int4*)(bufB + sw16(mt * 32 + l31, kk)));
            bf16x8 bw = as_frag(*(const int4*)(wp + ks * 16));
            acc = __builtin_amdgcn_mfma_f32_32x32x16_bf16(a, bw, acc, 0, 0, 0);
        }
#pragma unroll
        for (int reg = 0; reg < 16; ++reg) {
            const int m = mt * 32 + (reg & 3) + ((reg >> 2) << 3) + (lh << 2);
            atomicAdd(aggr + (size_t)sdst[m] * H + n, acc[reg]);
        }
    }
}

// ---------------------------------------------------------------- GRU via MFMA (64 nodes / block, 512 thr)
// Wave w owns packed cols w*64..w*64+63 = all 4 gates of h-slice w*16..w*16+15.
__global__ __launch_bounds__(512, 4) void gru_mfma(
        float* __restrict__ x, float* __restrict__ aggr, const float* __restrict__ inv_deg,
        const unsigned short* __restrict__ WG, const float* __restrict__ b3m,
        const float* __restrict__ bi, const float* __restrict__ bh) {
    __shared__ unsigned short bufA[64 * 256];   // 32 KB
    const int t = threadIdx.x;
    const int n0 = blockIdx.x * 64;
    const int wv = t >> 6, ln = t & 63, lrow = ln & 15, lq = ln >> 4;

    // stage A = bf16([aggr*inv_deg + b3 | x]): m = t>>3, k-slice q*32
    {
        const int m = t >> 3;
        const int q = t & 7;
        const int k0 = q * 32;
        const int node = n0 + m;
        if (q < 4) {
            const float scale = inv_deg[node];
            const float* src = aggr + (size_t)node * H + k0;
#pragma unroll
            for (int i = 0; i < 8; ++i) {
                float4 v = *(const float4*)(src + i * 4);
                const float4 bb = *(const float4*)(b3m + k0 + i * 4);
                v.x = v.x * scale + bb.x; v.y = v.y * scale + bb.y;
                v.z = v.z * scale + bb.z; v.w = v.w * scale + bb.w;
                uint2 o; o.x = pkbf(v.x, v.y); o.y = pkbf(v.z, v.w);
                *(uint2*)(bufA + sw_off(m, k0 + i * 4)) = o;
            }
        } else {
            const float* src = x + (size_t)node * H + (k0 - 128);
#pragma unroll
            for (int i = 0; i < 8; ++i) {
                float4 v = *(const float4*)(src + i * 4);
                uint2 o; o.x = pkbf(v.x, v.y); o.y = pkbf(v.z, v.w);
                *(uint2*)(bufA + sw_off(m, k0 + i * 4)) = o;
            }
        }
    }
    __syncthreads();

    const f32x4 zero = {0.f, 0.f, 0.f, 0.f};
    f32x4 acc[4][4];    // [m-tile][gate]
#pragma unroll
    for (int i = 0; i < 4; ++i)
#pragma unroll
        for (int j = 0; j < 4; ++j) acc[i][j] = zero;

    const unsigned short* wgp = WG + (size_t)(wv * 64 + lrow) * 256;
#pragma unroll
    for (int kq = 0; kq < 8; ++kq) {
        const int ko = kq * 32 + lq * 8;
        bf16x8 af[4], bfr[4];
#pragma unroll
        for (int tm = 0; tm < 4; ++tm)
            af[tm] = as_frag(*(const int4*)(bufA + sw_off(tm * 16 + lrow, ko)));
#pragma unroll
        for (int g = 0; g < 4; ++g)
            bfr[g] = as_frag(*(const int4*)(wgp + (size_t)g * 16 * 256 + ko));
#pragma unroll
        for (int tm = 0; tm < 4; ++tm)
#pragma unroll
            for (int g = 0; g < 4; ++g)
                acc[tm][g] = __builtin_amdgcn_mfma_f32_16x16x32_bf16(af[tm], bfr[g], acc[tm][g], 0, 0, 0);
    }

    // epilogue: thread-local gate mixing for h = wv*16 + lrow
    {
        const int h = wv * 16 + lrow;
        const float b_r = bi[h] + bh[h];
        const float b_z = bi[128 + h] + bh[128 + h];
        const float b_n = bi[256 + h];
        const float b_h = bh[256 + h];
#pragma unroll
        for (int tm = 0; tm < 4; ++tm) {
#pragma unroll
            for (int r = 0; r < 4; ++r) {
                const int node = n0 + tm * 16 + lq * 4 + r;
                const float irhr = acc[tm][0][r] + b_r;
                const float izhz = acc[tm][1][r] + b_z;
                const float inn  = acc[tm][2][r] + b_n;
                const float hn   = acc[tm][3][r] + b_h;
                const float rg = 1.f / (1.f + expf(-irhr));
                const float zg = 1.f / (1.f + expf(-izhz));
                const float ng = tanhf(inn + rg * hn);
                const float xo = x[(size_t)node * H + h];
                x[(size_t)node * H + h] = (1.f - zg) * ng + zg * xo;
                aggr[(size_t)node * H + h] = 0.f;   // re-zero for next step
            }
        }
    }
}

// ---------------------------------------------------------------- decoder via MFMA (64 masked ids / block)
__global__ __launch_bounds__(256, 4) void dec_mfma(
        const float* __restrict__ x,
        const unsigned short* __restrict__ W1T, const float* __restrict__ b1,
        const unsigned short* __restrict__ W2T, const float* __restrict__ b2,
        const float* __restrict__ W3, const float* __restrict__ b3,
        float* __restrict__ out) {
    __shared__ unsigned short buf[64 * 256];   // 32 KB
    const int t = threadIdx.x;
    const int id0 = blockIdx.x * 64;
    const int wv = t >> 6, ln = t & 63, lrow = ln & 15, lq = ln >> 4;
    const int nbase = wv * 64;

    // stage bf16(x) for 64 masked ids into buf[:, 0:128]
    {
        const int m = t >> 2, q = t & 3;
        const int id = id0 + m;
        const int node = (id >> 3) * NND + (id & 7);
        const float* src = x + (size_t)node * H + q * 32;
#pragma unroll
        for (int i = 0; i < 8; ++i) {
            float4 v = *(const float4*)(src + i * 4);
            uint2 o; o.x = pkbf(v.x, v.y); o.y = pkbf(v.z, v.w);
            *(uint2*)(buf + sw_off(m, q * 32 + i * 4)) = o;
        }
    }
    __syncthreads();

    const f32x4 zero = {0.f, 0.f, 0.f, 0.f};

    // ---- layer 1: K=128 -> 256 cols
    {
        f32x4 acc[4][4];
#pragma unroll
        for (int i = 0; i < 4; ++i)
#pragma unroll
            for (int j = 0; j < 4; ++j) acc[i][j] = zero;
#pragma unroll
        for (int kq = 0; kq < 4; ++kq) {
            const int ko = kq * 32 + lq * 8;
            bf16x8 af[4], bfr[4];
#pragma unroll
            for (int tm = 0; tm < 4; ++tm)
                af[tm] = as_frag(*(const int4*)(buf + sw_off(tm * 16 + lrow, ko)));
#pragma unroll
            for (int tn = 0; tn < 4; ++tn)
                bfr[tn] = as_frag(*(const int4*)(W1T + (size_t)(nbase + tn * 16 + lrow) * 128 + ko));
#pragma unroll
            for (int tm = 0; tm < 4; ++tm)
#pragma unroll
                for (int tn = 0; tn < 4; ++tn)
                    acc[tm][tn] = __builtin_amdgcn_mfma_f32_16x16x32_bf16(af[tm], bfr[tn], acc[tm][tn], 0, 0, 0);
        }
        __syncthreads();
#pragma unroll
        for (int tn = 0; tn < 4; ++tn) {
            const int n = nbase + tn * 16 + lrow;
            const float bias = b1[n];
#pragma unroll
            for (int tm = 0; tm < 4; ++tm)
#pragma unroll
                for (int r = 0; r < 4; ++r) {
                    const int m = tm * 16 + lq * 4 + r;
                    buf[sw_off(m, n)] = f2bf(fast_tanh(acc[tm][tn][r] + bias));
                }
        }
    }
    __syncthreads();

    // ---- layer 2: K=256 -> 256 cols
    {
        f32x4 acc[4][4];
#pragma unroll
        for (int i = 0; i < 4; ++i)
#pragma unroll
            for (int j = 0; j < 4; ++j) acc[i][j] = zero;
#pragma unroll
        for (int kq = 0; kq < 8; ++kq) {
            const int ko = kq * 32 + lq * 8;
            bf16x8 af[4], bfr[4];
#pragma unroll
            for (int tm = 0; tm < 4; ++tm)
                af[tm] = as_frag(*(const int4*)(buf + sw_off(tm * 16 + lrow, ko)));
#pragma unroll
            for (int tn = 0; tn < 4; ++tn)
                bfr[tn] = as_frag(*(const int4*)(W2T + (size_t)(nbase + tn * 16 + lrow) * 256 + ko));
#pragma unroll
            for (int tm = 0; tm < 4; ++tm)
#pragma unroll
                for (int tn = 0; tn < 4; ++tn)
                    acc[tm][tn] = __builtin_amdgcn_mfma_f32_16x16x32_bf16(af[tm], bfr[tn], acc[tm][tn], 0, 0, 0);
        }
        __syncthreads();
#pragma unroll
        for (int tn = 0; tn < 4; ++tn) {
            const int n = nbase + tn * 16 + lrow;
            const float bias = b2[n];
#pragma unroll
            for (int tm = 0; tm < 4; ++tm)
#pragma unroll
                for (int r = 0; r < 4; ++r) {
                    const int m = tm * 16 + lq * 4 + r;
                    buf[sw_off(m, n)] = f2bf(fast_tanh(acc[tm][tn][r] + bias));
                }
        }
    }
    __syncthreads();

    // ---- layer 3: 256 -> 1, 4 threads per id, shuffle reduce
    {
        const int m = t >> 2, p = t & 3;
        float s = 0.f;
#pragma unroll
        for (int i = 0; i < 64; ++i) {
            const int k = p * 64 + i;
            const float a = __uint_as_float((unsigned int)buf[sw_off(m, k)] << 16);
            s += a * W3[k];
        }
        s += __shfl_xor(s, 1);
        s += __shfl_xor(s, 2);
        if (p == 0) out[id0 + m] = s + b3[0];
    }
}

// ---------------------------------------------------------------- launch
extern "C" void kernel_launch(void* const* d_in, const int* in_sizes, int n_in,
                              void* d_out, int out_size, void* d_ws, size_t ws_size,
                              hipStream_t stream) {
    const float* obs    = (const float*)d_in[0];
    const int*   edges  = (const int*)  d_in[1];
    const float* enc_W  = (const float*)d_in[2];
    const float* enc_b  = (const float*)d_in[3];
    const float* msg_W1 = (const float*)d_in[4];
    const float* msg_b1 = (const float*)d_in[5];
    const float* msg_W2 = (const float*)d_in[6];
    const float* msg_b2 = (const float*)d_in[7];
    const float* msg_W3 = (const float*)d_in[8];
    const float* msg_b3 = (const float*)d_in[9];
    const float* gru_Wi = (const float*)d_in[10];
    const float* gru_Wh = (const float*)d_in[11];
    const float* gru_bi = (const float*)d_in[12];
    const float* gru_bh = (const float*)d_in[13];
    const float* dec_W1 = (const float*)d_in[14];
    const float* dec_b1 = (const float*)d_in[15];
    const float* dec_W2 = (const float*)d_in[16];
    const float* dec_b2 = (const float*)d_in[17];
    const float* dec_W3 = (const float*)d_in[18];
    const float* dec_b3 = (const float*)d_in[19];

    float* x       = (float*)d_ws;                 // BN*128 f32
    float* aggr    = x + (size_t)BN * H;           // BN*128 f32
    float* inv_deg = aggr + (size_t)BN * H;        // BN f32
    unsigned short* wbf = (unsigned short*)(inv_deg + BN);   // 1540096 bf16
    unsigned short* P   = wbf + 1540096;           // BN*512 bf16 (75.5 MB)

    hipMemsetAsync(aggr, 0, (size_t)BN * H * sizeof(float), stream);
    deg_kernel<<<(BGR + 255) / 256, 256, 0, stream>>>(edges, inv_deg);
    wt_kernel<<<1540096 / 256, 256, 0, stream>>>(msg_W1, msg_W2, msg_W3, gru_Wi, gru_Wh,
                                                 dec_W1, dec_W2, wbf);
    enc_kernel<<<BN * H / 256, 256, 0, stream>>>(obs, enc_W, enc_b, x);

    for (int s = 0; s < 4; ++s) {
        const unsigned short* W2T = wbf + 262144 + (size_t)s * 65536;
        const unsigned short* W3T = wbf + 524288 + (size_t)s * 32768;
        const unsigned short* WGs = wbf + 655360 + (size_t)s * 131072;
        const unsigned short* W1P = wbf + 1277952 + (size_t)s * 65536;
        proj_mfma<<<BN / 64, 512, 0, stream>>>(x, W1P, P);
        msg_mfma<<<ETOT / 64, 512, 0, stream>>>(
            P, edges,
            msg_b1 + (size_t)s * 256,
            W2T, msg_b2 + (size_t)s * 256,
            W3T,
            aggr);
        gru_mfma<<<BN / 64, 512, 0, stream>>>(
            x, aggr, inv_deg, WGs, msg_b3 + (size_t)s * 128,
            gru_bi + (size_t)s * 384, gru_bh + (size_t)s * 384);
    }

    dec_mfma<<<BGR * 8 / 64, 256, 0, stream>>>(
        x, wbf + 1179648, dec_b1, wbf + 1212416, dec_b2, dec_W3, dec_b3, (float*)d_out);
}